// Round 3
// baseline (623.170 us; speedup 1.0000x reference)
//
#include <hip/hip_runtime.h>

// ---------------- constants ----------------
#define BB   512   // batch
#define SS   256   // seq len
#define EE   128   // emb dim
#define HH   128   // per-dir hidden
#define LL   59    // labels
#define STARTL 57
#define STOPL  58
#define VOCAB 50000

typedef float  f32x4  __attribute__((ext_vector_type(4)));
typedef short  bf16x8 __attribute__((ext_vector_type(8)));
typedef short  s16x4  __attribute__((ext_vector_type(4)));

__device__ __forceinline__ short f2bf(float f) {
    unsigned u = __float_as_uint(f);
    u += 0x7FFFu + ((u >> 16) & 1u);   // RNE
    return (short)(u >> 16);
}
__device__ __forceinline__ float bf2f(unsigned short s) {
    return __uint_as_float(((unsigned)s) << 16);
}
__device__ __forceinline__ float sigf(float x) {
    float e = __builtin_amdgcn_exp2f(-1.44269504f * x);
    return __builtin_amdgcn_rcpf(1.0f + e);
}
__device__ __forceinline__ float tanhf_(float x) {
    float e = __builtin_amdgcn_exp2f(2.88539008f * x);
    return 1.0f - 2.0f * __builtin_amdgcn_rcpf(e + 1.0f);
}
__device__ __forceinline__ float wmax64(float v) {
    #pragma unroll
    for (int o = 32; o; o >>= 1) v = fmaxf(v, __shfl_xor(v, o));
    return v;
}
__device__ __forceinline__ float wsum64(float v) {
    #pragma unroll
    for (int o = 32; o; o >>= 1) v += __shfl_xor(v, o);
    return v;
}
// LDS-only barrier: global ops (prefetch loads, feat stores) stay in flight.
__device__ __forceinline__ void bar_lds() {
    asm volatile("s_waitcnt lgkmcnt(0)\n\ts_barrier" ::: "memory");
}

// ---------------- kernel 0: embed f32 -> bf16 table ----------------
__global__ __launch_bounds__(256) void conv_k(const float* __restrict__ embed,
                                              unsigned short* __restrict__ ebf)
{
    const int N4 = VOCAB * EE / 4;
    for (int i = blockIdx.x * blockDim.x + threadIdx.x; i < N4;
         i += gridDim.x * blockDim.x) {
        float4 v = ((const float4*)embed)[i];
        s16x4 s = { f2bf(v.x), f2bf(v.y), f2bf(v.z), f2bf(v.w) };
        ((s16x4*)ebf)[i] = s;
    }
}

// ---------------- kernel 1: persistent BiLSTM + fused projection ----------------
// 64 blocks (32 batch-tiles x 2 dirs), 8 waves. Embedding A-frags register-
// prefetched one step ahead (vmcnt waited at use, NOT at barrier). Barrier is
// lgkm-only; the only cross-wave dependency is the h tile in LDS.
__global__ __launch_bounds__(512, 1) void lstm_k(
    const int* __restrict__ x, const unsigned short* __restrict__ ebf,
    const float* __restrict__ Wih_f, const float* __restrict__ Whh_f,
    const float* __restrict__ bih_f, const float* __restrict__ bhh_f,
    const float* __restrict__ Wih_b, const float* __restrict__ Whh_b,
    const float* __restrict__ bih_b, const float* __restrict__ bhh_b,
    const float* __restrict__ h0, const float* __restrict__ c0,
    const float* __restrict__ Wout,
    unsigned short* __restrict__ fpF, unsigned short* __restrict__ fpB)
{
    const int tid = threadIdx.x;
    const int w  = tid >> 6;          // wave 0..7
    const int l  = tid & 63;
    const int qd = l >> 4;            // quad 0..3
    const int n  = l & 15;            // 0..15
    const int dir   = blockIdx.x & 1;
    const int b0    = (blockIdx.x >> 1) * 16;

    const float* Wih = dir ? Wih_b : Wih_f;
    const float* Whh = dir ? Whh_b : Whh_f;
    const float* bih = dir ? bih_b : bih_f;
    const float* bhh = dir ? bhh_b : bhh_f;
    unsigned short* fp = dir ? fpB : fpF;

    __shared__ short hbuf[2][2048];   // [octet 0..15][m 0..15][8] bf16
    __shared__ int   xsh[16 * 257];   // [m][t], stride 257 kills bank conflicts

    // --- stage x tile ---
    for (int i = tid; i < 16 * SS; i += 512) {
        const int m = i >> 8, t = i & 255;
        xsh[m * 257 + t] = x[(size_t)(b0 + m) * SS + t];
    }

    // --- weight fragments (pinned in VGPRs) ---
    bf16x8 fh[4][4], fx[4][4];        // [gate][kstep]
    float bias[4];
    #pragma unroll
    for (int g = 0; g < 4; ++g) {
        const int row = g * 128 + 16 * w + n;
        bias[g] = bih[row] + bhh[row];
        #pragma unroll
        for (int kk = 0; kk < 4; ++kk) {
            const float* ph = Whh + (size_t)row * 128 + kk * 32 + qd * 8;
            const float* px = Wih + (size_t)row * 128 + kk * 32 + qd * 8;
            bf16x8 vh, vx;
            #pragma unroll
            for (int j = 0; j < 8; ++j) { vh[j] = f2bf(ph[j]); vx[j] = f2bf(px[j]); }
            fh[g][kk] = vh; fx[g][kk] = vx;
        }
    }
    // --- Wout fragment (dir half), waves 4-7; col tile = w&3 ---
    bf16x8 wb[4];
    {
        const int col = (w & 3) * 16 + n;
        #pragma unroll
        for (int kk = 0; kk < 4; ++kk) {
            bf16x8 v = (bf16x8)0;
            if (col < LL) {
                const float* p = Wout + (size_t)col * 256 + dir * 128 + kk * 32 + qd * 8;
                #pragma unroll
                for (int j = 0; j < 8; ++j) v[j] = f2bf(p[j]);
            }
            wb[kk] = v;
        }
    }

    // --- c state: rows qd*4+r, col 16w+n ---
    float cst[4];
    #pragma unroll
    for (int r = 0; r < 4; ++r)
        cst[r] = c0[((size_t)dir * BB + b0 + qd * 4 + r) * HH + 16 * w + n];

    // h0 -> hbuf[0]
    {
        const int em  = l & 15;
        const int ek4 = w * 4 + (l >> 4);
        const float4 hv = *(const float4*)(h0 + ((size_t)dir * BB + b0 + em) * HH + ek4 * 4);
        s16x4 hs = { f2bf(hv.x), f2bf(hv.y), f2bf(hv.z), f2bf(hv.w) };
        *(s16x4*)&hbuf[0][((ek4 >> 1) * 16 + em) * 8 + (ek4 & 1) * 4] = hs;
    }
    __syncthreads();

    const int hid = 16 * w + n;
    const int hc  = hid >> 3, ho = hid & 7;

    // initial x A-frag (row b0+n, all 4 k-chunks)
    bf16x8 axc[4], axn[4];
    {
        const int xi = xsh[n * 257 + (dir ? SS - 1 : 0)];
        const unsigned short* er = ebf + (size_t)xi * EE + qd * 8;
        axc[0] = *(const bf16x8*)(er);
        axc[1] = *(const bf16x8*)(er + 32);
        axc[2] = *(const bf16x8*)(er + 64);
        axc[3] = *(const bf16x8*)(er + 96);
    }

    auto step = [&](int ts, bf16x8* axu, bf16x8* axp) {
        const int cur = ts & 1, nxt = cur ^ 1;

        // prefetch next x A-frag into axp (registers; waited at use next step)
        {
            const int tn  = (ts + 1 < SS) ? ts + 1 : ts;
            const int ten = dir ? (SS - 1 - tn) : tn;
            const int xi  = xsh[n * 257 + ten];
            const unsigned short* er = ebf + (size_t)xi * EE + qd * 8;
            axp[0] = *(const bf16x8*)(er);
            axp[1] = *(const bf16x8*)(er + 32);
            axp[2] = *(const bf16x8*)(er + 64);
            axp[3] = *(const bf16x8*)(er + 96);
        }

        // h A-frags from LDS
        bf16x8 ah[4];
        #pragma unroll
        for (int kk = 0; kk < 4; ++kk)
            ah[kk] = *(const bf16x8*)&hbuf[cur][((kk * 4 + qd) * 16 + n) * 8];

        f32x4 acc[4] = { {0,0,0,0}, {0,0,0,0}, {0,0,0,0}, {0,0,0,0} };
        // x-half first: regs ready at step top, runs while ds_read completes
        #pragma unroll
        for (int kk = 0; kk < 4; ++kk) {
            #pragma unroll
            for (int g = 0; g < 4; ++g)
                acc[g] = __builtin_amdgcn_mfma_f32_16x16x32_bf16(axu[kk], fx[g][kk], acc[g], 0, 0, 0);
        }
        #pragma unroll
        for (int kk = 0; kk < 4; ++kk) {
            #pragma unroll
            for (int g = 0; g < 4; ++g)
                acc[g] = __builtin_amdgcn_mfma_f32_16x16x32_bf16(ah[kk], fh[g][kk], acc[g], 0, 0, 0);
        }

        // fused projection of h_{ts-1} (waves 4-7; reuses ah); bf16 stores
        if (w >= 4 && ts > 0) {
            f32x4 pa = {0, 0, 0, 0};
            #pragma unroll
            for (int kk = 0; kk < 4; ++kk)
                pa = __builtin_amdgcn_mfma_f32_16x16x32_bf16(ah[kk], wb[kk], pa, 0, 0, 0);
            const int tep = dir ? (SS - ts) : (ts - 1);
            #pragma unroll
            for (int r = 0; r < 4; ++r)
                fp[((size_t)(b0 + qd * 4 + r) * SS + tep) * 64 + (w & 3) * 16 + n]
                    = (unsigned short)f2bf(pa[r]);
        }

        // gates + state update + h writes
        #pragma unroll
        for (int r = 0; r < 4; ++r) {
            const float iv = sigf(acc[0][r] + bias[0]);
            const float fv = sigf(acc[1][r] + bias[1]);
            const float gv = tanhf_(acc[2][r] + bias[2]);
            const float ov = sigf(acc[3][r] + bias[3]);
            const float cc = fv * cst[r] + iv * gv;
            cst[r] = cc;
            hbuf[nxt][(hc * 16 + qd * 4 + r) * 8 + ho] = f2bf(ov * tanhf_(cc));
        }
        bar_lds();
    };

    for (int ts = 0; ts < SS; ts += 2) {
        step(ts,     axc, axn);
        step(ts + 1, axn, axc);
    }

    // epilogue: project final h (hbuf[0], SS even)
    if (w >= 4) {
        f32x4 pa = {0, 0, 0, 0};
        #pragma unroll
        for (int kk = 0; kk < 4; ++kk) {
            bf16x8 a = *(const bf16x8*)&hbuf[0][((kk * 4 + qd) * 16 + n) * 8];
            pa = __builtin_amdgcn_mfma_f32_16x16x32_bf16(a, wb[kk], pa, 0, 0, 0);
        }
        const int tep = dir ? 0 : (SS - 1);
        #pragma unroll
        for (int r = 0; r < 4; ++r)
            fp[((size_t)(b0 + qd * 4 + r) * SS + tep) * 64 + (w & 3) * 16 + n]
                = (unsigned short)f2bf(pa[r]);
    }
}

// ---------------- kernel 2: CRF forward + gold + reduce ----------------
__global__ __launch_bounds__(256, 2) void crf_k(
    const unsigned short* __restrict__ fpF, const unsigned short* __restrict__ fpB,
    const float* __restrict__ bout, const int* __restrict__ y,
    const float* __restrict__ trans, float* __restrict__ out)
{
    const int tid = threadIdx.x, w = tid >> 6, j = tid & 63;
    const int b = blockIdx.x * 4 + w;
    const size_t bS = (size_t)b * SS;
    const bool valid = (j < LL);
    const int  jr = valid ? j : (LL - 1);

    float etr[LL];
    #pragma unroll
    for (int i = 0; i < LL; ++i) {
        const float t = trans[jr * LL + i];
        etr[i] = valid ? __builtin_amdgcn_exp2f(t * 1.44269504f) : 0.0f;
    }
    const float bo = valid ? bout[jr] : 0.0f;

    float alpha = valid ? ((j == STARTL) ? 0.0f : -10000.0f) : -1e30f;

    float fF[4], fB[4];
    #pragma unroll
    for (int q = 0; q < 4; ++q) {
        fF[q] = bf2f(fpF[(bS + q) * 64 + j]);
        fB[q] = bf2f(fpB[(bS + q) * 64 + j]);
    }

    for (int t0 = 0; t0 < SS; t0 += 4) {
        float nF[4] = {0,0,0,0}, nB[4] = {0,0,0,0};
        if (t0 + 4 < SS) {
            #pragma unroll
            for (int q = 0; q < 4; ++q) {
                nF[q] = bf2f(fpF[(bS + t0 + 4 + q) * 64 + j]);
                nB[q] = bf2f(fpB[(bS + t0 + 4 + q) * 64 + j]);
            }
        }
        #pragma unroll
        for (int u = 0; u < 4; ++u) {
            const float K = fmaxf(
                __uint_as_float(__builtin_amdgcn_readlane(__float_as_uint(alpha), 1)),
                __uint_as_float(__builtin_amdgcn_readlane(__float_as_uint(alpha), STARTL)));
            const float ea = __builtin_amdgcn_exp2f((alpha - K) * 1.44269504f);
            float d0 = 0.0f, d1 = 0.0f, d2 = 0.0f, d3 = 0.0f;
            #pragma unroll
            for (int i = 0; i < LL; i += 4) {
                d0 += etr[i] * __uint_as_float(__builtin_amdgcn_readlane(__float_as_uint(ea), i));
                if (i + 1 < LL) d1 += etr[i+1] * __uint_as_float(__builtin_amdgcn_readlane(__float_as_uint(ea), i+1));
                if (i + 2 < LL) d2 += etr[i+2] * __uint_as_float(__builtin_amdgcn_readlane(__float_as_uint(ea), i+2));
                if (i + 3 < LL) d3 += etr[i+3] * __uint_as_float(__builtin_amdgcn_readlane(__float_as_uint(ea), i+3));
            }
            const float dot = (d0 + d1) + (d2 + d3);
            alpha = (fF[u] + fB[u] + bo) + K +
                    0.69314718f * __builtin_amdgcn_logf(dot);
        }
        #pragma unroll
        for (int q = 0; q < 4; ++q) { fF[q] = nF[q]; fB[q] = nB[q]; }
    }

    const float v  = alpha + trans[STOPL * LL + jr];
    const float m2 = wmax64(v);
    const float s  = wsum64(__builtin_amdgcn_exp2f((v - m2) * 1.44269504f));
    const float fwd = m2 + 0.69314718f * __builtin_amdgcn_logf(s);

    float g = 0.0f;
    #pragma unroll
    for (int q = 0; q < 4; ++q) {
        const int t  = q * 64 + j;
        const int yt = y[bS + t];
        const int yp = t ? y[bS + t - 1] : STARTL;
        g += bf2f(fpF[(bS + t) * 64 + yt]) + bf2f(fpB[(bS + t) * 64 + yt])
           + bout[yt] + trans[yt * LL + yp];
    }
    g = wsum64(g);

    if (j == 0) {
        g += trans[STOPL * LL + y[bS + SS - 1]];
        atomicAdd(out, fwd - g);
    }
}

// ---------------- launcher ----------------
extern "C" void kernel_launch(void* const* d_in, const int* in_sizes, int n_in,
                              void* d_out, int out_size, void* d_ws, size_t ws_size,
                              hipStream_t stream)
{
    (void)in_sizes; (void)n_in; (void)out_size; (void)ws_size;
    const int*   x      = (const int*)  d_in[0];
    const int*   y      = (const int*)  d_in[1];
    const float* embed  = (const float*)d_in[2];
    const float* Wih_f  = (const float*)d_in[3];
    const float* Whh_f  = (const float*)d_in[4];
    const float* bih_f  = (const float*)d_in[5];
    const float* bhh_f  = (const float*)d_in[6];
    const float* Wih_b  = (const float*)d_in[7];
    const float* Whh_b  = (const float*)d_in[8];
    const float* bih_b  = (const float*)d_in[9];
    const float* bhh_b  = (const float*)d_in[10];
    const float* Wout   = (const float*)d_in[11];
    const float* bout   = (const float*)d_in[12];
    const float* trans  = (const float*)d_in[13];
    const float* h0     = (const float*)d_in[14];
    const float* c0     = (const float*)d_in[15];

    unsigned short* ebf = (unsigned short*)d_ws;                                  // 12.8 MiB
    unsigned short* fpF = (unsigned short*)((char*)d_ws + (size_t)16 * 1024 * 1024); // 16 MiB
    unsigned short* fpB = (unsigned short*)((char*)d_ws + (size_t)32 * 1024 * 1024); // 16 MiB

    hipMemsetAsync(d_out, 0, sizeof(float), stream);
    conv_k<<<2048, 256, 0, stream>>>(embed, ebf);
    lstm_k<<<64, 512, 0, stream>>>(x, ebf, Wih_f, Whh_f, bih_f, bhh_f,
                                   Wih_b, Whh_b, bih_b, bhh_b, h0, c0,
                                   Wout, fpF, fpB);
    crf_k<<<BB / 4, 256, 0, stream>>>(fpF, fpB, bout, y, trans, (float*)d_out);
}